// Round 18
// baseline (92.569 us; speedup 1.0000x reference)
//
#include <hip/hip_runtime.h>
#include <hip/hip_fp16.h>
#include <math.h>

#define C_CH       64
#define F_FRAMES   999
#define TOTAL_SAMP 320000
#define FRAME_LEN  640
#define STEP       320
#define N2         512      // complex FFT size (real FFT 1024)
#define NBINS      513
#define NMEL       40
#define NMFCC      13
#define CHPG       16       // channels per block (one 64B line)
#define NCHG       4        // channel groups
#define NBLK       (F_FRAMES * NCHG)   // 3996 blocks
#define MELW_STRIDE 72      // multiple of 4
#define SPAD       576      // 512 + 64 pad half2 per channel buffer (2304 B)
#define SSTR       654      // halfs per channel row (640 + pad, even)
#define ROWH2      (SSTR / 2)          // 327 half2 per staging row
#define PITCH_H2   (4 * ROWH2)         // 1308 half2: one wave's 4 rows = its FFT region

#define TWO_PI_F 6.28318530717958647692f
#define LN2_F    0.69314718055994530942f

// d_ws float layout (all offsets multiples of 4 -> float4-aligned)
#define WS_HANN   0        // 640
#define WS_DCT    640      // 520  (pre-scaled by ln2; lm holds log2)
#define WS_MSTART 1160     // 40 ints (lo4, 4-aligned bin start)
#define WS_MELW   1200     // 40*72 = 2880, zero-padded rows, PRE-SCALED by 0.5
#define WS_TOTAL  4080

__global__ __launch_bounds__(256)
void setup_tables(float* __restrict__ ws) {
    __shared__ float wloc[NBINS];
    __shared__ int   chloc[NBINS];
    __shared__ int   lo_s[NMEL];
    const int tid = threadIdx.x;

    if (tid < NMEL) lo_s[tid] = 0x7fffffff;

    for (int n = tid; n < FRAME_LEN; n += 256)
        ws[WS_HANN + n] = 0.5f - 0.5f * cosf((float)n * (TWO_PI_F / 640.0f));

    // DCT pre-scaled by ln2 (kernel's lm holds log2(mel))
    for (int idx = tid; idx < NMFCC * NMEL; idx += 256) {
        int j = idx / NMEL, m = idx - j * NMEL;
        ws[WS_DCT + idx] = LN2_F * 0.223606797749978969f *
            cosf((float)(M_PI * (double)j * ((double)m + 0.5) / (double)NMEL));
    }

    for (int idx = tid; idx < NMEL * MELW_STRIDE; idx += 256)
        ws[WS_MELW + idx] = 0.0f;

    // dense per-bin (ch, w), replicating TF MfccMelFilterbank
    const double mel_lo  = 1127.0 * log1p(20.0 / 700.0);
    const double mel_hi  = 1127.0 * log1p(7600.0 / 700.0);
    const double spacing = (mel_hi - mel_lo) / (NMEL + 1);
    for (int i = tid; i < NBINS; i += 256) {
        if (i < 2 || i > 486) {      // start_index=2, end_index=486
            chloc[i] = -100; wloc[i] = 0.0f;
        } else {
            double melf = 1127.0 * log1p((double)i * 15.625 / 700.0);
            int ch = 0;
            while (ch < NMEL && (mel_lo + spacing * (ch + 1)) < melf) ch++;
            ch -= 1;                 // may be -1
            chloc[i] = ch;
            wloc[i]  = (float)((mel_lo + spacing * (ch + 2) - melf) / spacing);
        }
    }
    __syncthreads();

    // per-channel lo via parallel atomicMin
    for (int i = 2 + tid; i <= 486; i += 256) {
        int ch = chloc[i];
        if (ch >= 0)       atomicMin(&lo_s[ch], i);
        if (ch + 1 < NMEL) atomicMin(&lo_s[ch + 1], i);
    }
    __syncthreads();
    if (tid < NMEL) {
        int lo  = lo_s[tid];
        int lo4 = (lo == 0x7fffffff) ? 0 : (lo & ~3);
        lo_s[tid] = lo4;
        ((int*)(ws + WS_MSTART))[tid] = lo4;
    }
    __syncthreads();

    // scatter weights (x0.5: kernel computes 2X in the rfft unpack)
    for (int i = 2 + tid; i <= 486; i += 256) {
        int ch = chloc[i]; float wgt = wloc[i];
        if (ch >= 0)
            ws[WS_MELW + ch * MELW_STRIDE + (i - lo_s[ch])] = 0.5f * wgt;
        if (ch + 1 < NMEL)
            ws[WS_MELW + (ch + 1) * MELW_STRIDE + (i - lo_s[ch + 1])] = 0.5f * (1.0f - wgt);
    }
}

// ---- packed-f32 (VOP3P) complex helpers ----
typedef float vf2 __attribute__((ext_vector_type(2)));
union f2u { float2 f; vf2 v; };
__device__ __forceinline__ vf2 V(float2 a){ f2u u; u.f = a; return u.v; }
__device__ __forceinline__ float2 F(vf2 a){ f2u u; u.v = a; return u.f; }

__device__ __forceinline__ float2 pkadd(float2 af, float2 bf){
    vf2 d, a = V(af), b = V(bf);
    asm("v_pk_add_f32 %0, %1, %2" : "=v"(d) : "v"(a), "v"(b));
    return F(d);
}
__device__ __forceinline__ float2 pksub(float2 af, float2 bf){
    vf2 d, a = V(af), b = V(bf);
    asm("v_pk_add_f32 %0, %1, %2 neg_lo:[0,1] neg_hi:[0,1]" : "=v"(d) : "v"(a), "v"(b));
    return F(d);
}
// d = a + (-i)*b
__device__ __forceinline__ float2 pkaddmi(float2 af, float2 bf){
    vf2 d, a = V(af), b = V(bf);
    asm("v_pk_add_f32 %0, %1, %2 op_sel:[0,1] op_sel_hi:[1,0] neg_hi:[0,1]" : "=v"(d) : "v"(a), "v"(b));
    return F(d);
}
// d = a - (-i)*b
__device__ __forceinline__ float2 pksubmi(float2 af, float2 bf){
    vf2 d, a = V(af), b = V(bf);
    asm("v_pk_add_f32 %0, %1, %2 op_sel:[0,1] op_sel_hi:[1,0] neg_lo:[0,1]" : "=v"(d) : "v"(a), "v"(b));
    return F(d);
}
// d = a * w (complex, 2 ops)
__device__ __forceinline__ float2 cmulpk(float2 af, float2 wf){
    vf2 d, a = V(af), w = V(wf);
    asm("v_pk_mul_f32 %0, %1, %2 op_sel:[0,0] op_sel_hi:[0,1]" : "=v"(d) : "v"(a), "v"(w));
    asm("v_pk_fma_f32 %0, %1, %2, %0 op_sel:[1,1,0] op_sel_hi:[1,0,1] neg_lo:[1,0,0] neg_hi:[0,0,0]"
        : "+v"(d) : "v"(a), "v"(w));
    return F(d);
}
// E = (zk.x + zm.x, zk.y - zm.y)
__device__ __forceinline__ float2 pkE(float2 zkf, float2 zmf){
    vf2 d, zk = V(zkf), zm = V(zmf);
    asm("v_pk_add_f32 %0, %1, %2 neg_hi:[0,1]" : "=v"(d) : "v"(zk), "v"(zm));
    return F(d);
}
// O = (zk.y + zm.y, zm.x - zk.x)
__device__ __forceinline__ float2 pkO(float2 zkf, float2 zmf){
    vf2 d, zk = V(zkf), zm = V(zmf);
    asm("v_pk_add_f32 %0, %1, %2 op_sel:[1,1] op_sel_hi:[0,0] neg_hi:[1,0]" : "=v"(d) : "v"(zk), "v"(zm));
    return F(d);
}

#define S8C 0.70710678118654752440f

__device__ __forceinline__ void dft8(float2 v[8]) {
    float2 b0=pkadd(v[0],v[4]), b4=pksub(v[0],v[4]);
    float2 b1=pkadd(v[1],v[5]), b5=pksub(v[1],v[5]);
    float2 b2=pkadd(v[2],v[6]), b6=pksub(v[2],v[6]);
    float2 b3=pkadd(v[3],v[7]), b7=pksub(v[3],v[7]);
    float2 c0=pkadd(b0,b2), c2=pksub(b0,b2);
    float2 c1=pkadd(b1,b3), c3=pksub(b1,b3);
    float2 c4=pkaddmi(b4,b6), c6=pksubmi(b4,b6);
    float2 c5=pkaddmi(b5,b7), c7=pksubmi(b5,b7);
    float2 w1c5 = cmulpk(c5, make_float2(S8C, -S8C));
    float2 w3c7 = cmulpk(c7, make_float2(-S8C, -S8C));
    v[0]=pkadd(c0,c1);   v[4]=pksub(c0,c1);
    v[2]=pkaddmi(c2,c3); v[6]=pksubmi(c2,c3);
    v[1]=pkadd(c4,w1c5); v[5]=pksub(c4,w1c5);
    v[3]=pkadd(c6,w3c7); v[7]=pksub(c6,w3c7);
}

// dft8 specialized for v[5]=v[6]=v[7]=0
__device__ __forceinline__ void dft8_first(float2 v[8]) {
    float2 b0=pkadd(v[0],v[4]), b4=pksub(v[0],v[4]);
    float2 c0=pkadd(b0,v[2]), c2=pksub(b0,v[2]);
    float2 c1=pkadd(v[1],v[3]), c3=pksub(v[1],v[3]);
    float2 c4=pkaddmi(b4,v[2]), c6=pksubmi(b4,v[2]);
    float2 c5=pkaddmi(v[1],v[3]), c7=pksubmi(v[1],v[3]);
    float2 w1c5 = cmulpk(c5, make_float2(S8C, -S8C));
    float2 w3c7 = cmulpk(c7, make_float2(-S8C, -S8C));
    v[0]=pkadd(c0,c1);   v[4]=pksub(c0,c1);
    v[2]=pkaddmi(c2,c3); v[6]=pksubmi(c2,c3);
    v[1]=pkadd(c4,w1c5); v[5]=pksub(c4,w1c5);
    v[3]=pkadd(c6,w3c7); v[7]=pksub(c6,w3c7);
}

__global__ __launch_bounds__(256, 4)
void mfcc_kernel(const float* __restrict__ wave, const float* __restrict__ ws,
                 float* __restrict__ out) {
    // pool: staging = 16 rows x 327 half2 (20928 B); FFT phase: wave w's region =
    // its OWN 4 rows [w*1308, w*1308+1308) — SA/SB (1152 half2) fit inside.
    __shared__ __align__(16) __half2 pool[CHPG * ROWH2];   // 20928 B
    __shared__ __align__(16) float   lmall[8 * NMEL];      // 1280 B

    const int tid = threadIdx.x;
    // bijective chunked XCD swizzle: nwg = 3996 = 8*499 + 4
    const int b    = blockIdx.x;
    const int xcd  = b & 7;
    const int wgid = (xcd < 4 ? xcd * 500 : 2000 + (xcd - 4) * 499) + (b >> 3);
    const int cg   = wgid / 999;         // channel group 0..3
    const int f    = wgid - cg * 999;    // frame
    const int c0   = cg * CHPG;
    const int w    = tid >> 6;           // wave id 0..3
    const int l    = tid & 63;           // lane

    // ---- coalesced stage: 640 rows x 64B, Hann applied, transposed [ch][t] half ----
    {
        const float4* wp4 = (const float4*)(wave + (size_t)f * STEP * C_CH) + cg * 4;
        const float*  hannf = ws + WS_HANN;
        #pragma unroll
        for (int m = 0; m < 5; ++m) {
            const int j = tid + 256 * m;     // 0..1279
            const int p = j >> 2, g = j & 3; // p = t-pair 0..319
            float4 x0 = wp4[(size_t)(2 * p)     * 16 + g];
            float4 x1 = wp4[(size_t)(2 * p + 1) * 16 + g];
            float  h0 = hannf[2 * p], h1 = hannf[2 * p + 1];
            pool[(4*g+0)*ROWH2 + p] = __floats2half2_rn(x0.x * h0, x1.x * h1);
            pool[(4*g+1)*ROWH2 + p] = __floats2half2_rn(x0.y * h0, x1.y * h1);
            pool[(4*g+2)*ROWH2 + p] = __floats2half2_rn(x0.z * h0, x1.z * h1);
            pool[(4*g+3)*ROWH2 + p] = __floats2half2_rn(x0.w * h0, x1.w * h1);
        }
    }
    __syncthreads();
    // ---- below: strictly wave-private LDS (own 4 rows only); no more barriers ----

    // pre-pull q=1 channels (rows 4w+2, 4w+3) — clobbered by own q=0 FFT writes
    __half2 sA1[5], sB1[5];
    {
        const int r2 = (4*w+2)*ROWH2, r3 = (4*w+3)*ROWH2;
        #pragma unroll
        for (int r = 0; r < 5; ++r) {
            sA1[r] = pool[r2 + l + 64*r];
            sB1[r] = pool[r3 + l + 64*r];
        }
    }

    __half2* SA   = pool + w * PITCH_H2;
    __half2* SB   = SA + SPAD;
    float*   magA = (float*)SA;          // overlays (576 floats each)
    float*   magB = (float*)SB;
    float*   lmA  = lmall + (2 * w) * NMEL;
    float*   lmB  = lmA + NMEL;

    // per-lane twiddle bases: W = e^{-i theta} = (cos, -sin)
    float s2a, c2a, s3a, c3a, sua, cua;
    __sincosf((float)(l & 7) * (TWO_PI_F / 64.0f),  &s2a, &c2a);
    __sincosf((float)l       * (TWO_PI_F / 512.0f), &s3a, &c3a);
    __sincosf((float)l       * (TWO_PI_F / 1024.0f),&sua, &cua);
    const float2 tb2 = make_float2(c2a, -s2a);
    const float2 tb3 = make_float2(c3a, -s3a);
    const float2 bu  = make_float2(cua, -sua);

    // W16^r = (cos(pi r/8), -sin(pi r/8))
    const float C16[8] = {1.0f, 0.923879533f, 0.707106781f, 0.382683432f,
                          0.0f, -0.382683432f, -0.707106781f, -0.923879533f};
    const float S16[8] = {0.0f, 0.382683432f, 0.707106781f, 0.923879533f,
                          1.0f, 0.923879533f, 0.707106781f, 0.382683432f};

    // hoisted q-invariant twiddle ladders + unpack twiddles
    float2 t2p[7], t3p[7], twh[8];
    t2p[0] = tb2; t3p[0] = tb3;
    #pragma unroll
    for (int r = 1; r < 7; ++r) {
        t2p[r] = cmulpk(t2p[r - 1], tb2);
        t3p[r] = cmulpk(t3p[r - 1], tb3);
    }
    #pragma unroll
    for (int r = 0; r < 8; ++r)
        twh[r] = cmulpk(bu, make_float2(C16[r], -S16[r]));   // W1024^{l+64r}

    const int src = (64 - l) & 63;

    #pragma unroll 1
    for (int q = 0; q < 2; ++q) {
        const int chA = 4 * w + 2 * q;   // local channels chA, chA+1

        float2 a[8], c[8];
        if (q == 0) {
            const __half2* rA = pool + (4*w)*ROWH2;
            const __half2* rB = pool + (4*w+1)*ROWH2;
            #pragma unroll
            for (int r = 0; r < 8; ++r) {
                if (r < 5) {
                    a[r] = __half22float2(rA[l + 64*r]);
                    c[r] = __half22float2(rB[l + 64*r]);
                } else { a[r] = make_float2(0.f, 0.f); c[r] = make_float2(0.f, 0.f); }
            }
        } else {
            #pragma unroll
            for (int r = 0; r < 8; ++r) {
                if (r < 5) {
                    a[r] = __half22float2(sA1[r]);
                    c[r] = __half22float2(sB1[r]);
                } else { a[r] = make_float2(0.f, 0.f); c[r] = make_float2(0.f, 0.f); }
            }
        }

        // ---- stage 1 ----
        dft8_first(a); dft8_first(c);
        #pragma unroll
        for (int k = 0; k < 8; ++k) {
            const int i = 8 * l + k;
            SA[i + (i >> 3)] = __floats2half2_rn(a[k].x, a[k].y);
            SB[i + (i >> 3)] = __floats2half2_rn(c[k].x, c[k].y);
        }

        // ---- stage 2: twiddle W64^{(l&7) r} ----
        #pragma unroll
        for (int r = 0; r < 8; ++r) {
            const int i = l + 64 * r;
            a[r] = __half22float2(SA[i + (i >> 3)]);
            c[r] = __half22float2(SB[i + (i >> 3)]);
        }
        #pragma unroll
        for (int r = 1; r < 8; ++r) { a[r] = cmulpk(a[r], t2p[r-1]); c[r] = cmulpk(c[r], t2p[r-1]); }
        dft8(a); dft8(c);
        {
            const int idxD = ((l >> 3) << 6) + (l & 7);
            #pragma unroll
            for (int k = 0; k < 8; ++k) {
                const int i = idxD + 8 * k;
                SA[i + (i >> 3)] = __floats2half2_rn(a[k].x, a[k].y);
                SB[i + (i >> 3)] = __floats2half2_rn(c[k].x, c[k].y);
            }
        }

        // ---- stage 3: twiddle W512^{l r}; result in registers ----
        #pragma unroll
        for (int r = 0; r < 8; ++r) {
            const int i = l + 64 * r;
            a[r] = __half22float2(SA[i + (i >> 3)]);
            c[r] = __half22float2(SB[i + (i >> 3)]);
        }
        #pragma unroll
        for (int r = 1; r < 8; ++r) { a[r] = cmulpk(a[r], t3p[r-1]); c[r] = cmulpk(c[r], t3p[r-1]); }
        dft8(a); dft8(c);
        // lane l holds Z[l + 64k] in a[k]/c[k]

        // ---- rfft unpack + magnitude, shuffles batched in groups of 4 ----
        #pragma unroll
        for (int h = 0; h < 2; ++h) {
            float2 ta[4], tc[4];
            #pragma unroll
            for (int j = 0; j < 4; ++j) {
                const int r = 4 * h + j;
                ta[j].x = __shfl(a[7 - r].x, src); ta[j].y = __shfl(a[7 - r].y, src);
                tc[j].x = __shfl(c[7 - r].x, src); tc[j].y = __shfl(c[7 - r].y, src);
            }
            if (l == 0) {
                #pragma unroll
                for (int j = 0; j < 4; ++j) {
                    const int r = 4 * h + j;
                    ta[j] = a[(8 - r) & 7]; tc[j] = c[(8 - r) & 7];
                }
            }
            #pragma unroll
            for (int j = 0; j < 4; ++j) {
                const int r = 4 * h + j;
                float2 Ea = pkE(a[r], ta[j]), Oa = pkO(a[r], ta[j]);
                float2 Xa = pkadd(Ea, cmulpk(Oa, twh[r]));
                float2 Ec = pkE(c[r], tc[j]), Oc = pkO(c[r], tc[j]);
                float2 Xc = pkadd(Ec, cmulpk(Oc, twh[r]));
                magA[l + 64 * r] = __builtin_amdgcn_sqrtf(Xa.x * Xa.x + Xa.y * Xa.y);
                magB[l + 64 * r] = __builtin_amdgcn_sqrtf(Xc.x * Xc.x + Xc.y * Xc.y);
            }
        }
        magA[512 + l] = (l == 0) ? 2.0f * fabsf(a[0].x - a[0].y) : 0.0f;
        magB[512 + l] = (l == 0) ? 2.0f * fabsf(c[0].x - c[0].y) : 0.0f;

        // ---- mel: lanes<40, shared weight row, both channels; lm holds log2 ----
        if (l < NMEL) {
            const int lo4 = ((const int*)(ws + WS_MSTART))[l];
            const float4* wrow = (const float4*)(ws + WS_MELW + l * MELW_STRIDE);
            const float4* mrA  = (const float4*)(magA + lo4);
            const float4* mrB  = (const float4*)(magB + lo4);
            float accA = 0.0f, accB = 0.0f;
            #pragma unroll
            for (int j = 0; j < MELW_STRIDE / 4; ++j) {
                float4 wv = wrow[j];
                float4 va = mrA[j], vb = mrB[j];
                accA += wv.x * va.x + wv.y * va.y + wv.z * va.z + wv.w * va.w;
                accB += wv.x * vb.x + wv.y * vb.y + wv.z * vb.z + wv.w * vb.w;
            }
            lmA[l] = __builtin_amdgcn_logf(accA + 1e-12f);   // log2; ln2 folded into DCT
            lmB[l] = __builtin_amdgcn_logf(accB + 1e-12f);
        }

        // ---- DCT + clip + store (lanes 0..12), both channels ----
        if (l < NMFCC) {
            const float4* drow = (const float4*)(ws + WS_DCT + l * NMEL);
            const float4* lrA  = (const float4*)lmA;
            const float4* lrB  = (const float4*)lmB;
            float accA = 0.0f, accB = 0.0f;
            #pragma unroll
            for (int j = 0; j < NMEL / 4; ++j) {
                float4 dv = drow[j];
                float4 va = lrA[j], vb = lrB[j];
                accA += dv.x * va.x + dv.y * va.y + dv.z * va.z + dv.w * va.w;
                accB += dv.x * vb.x + dv.y * vb.y + dv.z * vb.z + dv.w * vb.w;
            }
            accA = fminf(10.0f, fmaxf(-10.0f, accA));
            accB = fminf(10.0f, fmaxf(-10.0f, accB));
            out[((size_t)(c0 + chA)     * F_FRAMES + f) * NMFCC + l] = accA;
            out[((size_t)(c0 + chA + 1) * F_FRAMES + f) * NMFCC + l] = accB;
        }
    }
}

extern "C" void kernel_launch(void* const* d_in, const int* in_sizes, int n_in,
                              void* d_out, int out_size, void* d_ws, size_t ws_size,
                              hipStream_t stream) {
    const float* wave = (const float*)d_in[0];
    float* out = (float*)d_out;
    float* ws  = (float*)d_ws;
    hipLaunchKernelGGL(setup_tables, dim3(1), dim3(256), 0, stream, ws);
    hipLaunchKernelGGL(mfcc_kernel, dim3(NBLK), dim3(256), 0, stream, wave, ws, out);
}

// Round 19
// 79.210 us; speedup vs baseline: 1.1687x; 1.1687x over previous
//
#include <hip/hip_runtime.h>
#include <hip/hip_fp16.h>
#include <math.h>

#define C_CH       64
#define F_FRAMES   999
#define TOTAL_SAMP 320000
#define FRAME_LEN  640
#define STEP       320
#define N2         512      // complex FFT size (real FFT 1024)
#define NBINS      513
#define NMEL       40
#define NMFCC      13
#define CHPG       16       // channels per block (one 64B line)
#define NCHG       4        // channel groups
#define NBLK       (F_FRAMES * NCHG)   // 3996 blocks
#define MELW_STRIDE 72      // multiple of 4
#define SPAD       576      // 512 + 64 pad half2 per channel buffer (2304 B)
#define SSTR       654      // halfs per channel row (640 + pad, even)
#define ROWH2      (SSTR / 2)          // 327 half2 per staging row
#define PITCH_H2   (4 * ROWH2)         // 1308 half2: one wave's 4 rows = its FFT region

#define TWO_PI_F 6.28318530717958647692f
#define LN2_F    0.69314718055994530942f

// d_ws float layout (all offsets multiples of 4 -> float4-aligned)
#define WS_HANN   0        // 640
#define WS_DCT    640      // 520  (pre-scaled by ln2; lm holds log2)
#define WS_MSTART 1160     // 40 ints (lo4, 4-aligned bin start)
#define WS_MELW   1200     // 40*72 = 2880, zero-padded rows, PRE-SCALED by 0.5
#define WS_TOTAL  4080

__global__ __launch_bounds__(256)
void setup_tables(float* __restrict__ ws) {
    __shared__ float wloc[NBINS];
    __shared__ int   chloc[NBINS];
    __shared__ int   lo_s[NMEL];
    const int tid = threadIdx.x;

    if (tid < NMEL) lo_s[tid] = 0x7fffffff;

    for (int n = tid; n < FRAME_LEN; n += 256)
        ws[WS_HANN + n] = 0.5f - 0.5f * cosf((float)n * (TWO_PI_F / 640.0f));

    // DCT pre-scaled by ln2 (kernel's lm holds log2(mel))
    for (int idx = tid; idx < NMFCC * NMEL; idx += 256) {
        int j = idx / NMEL, m = idx - j * NMEL;
        ws[WS_DCT + idx] = LN2_F * 0.223606797749978969f *
            cosf((float)(M_PI * (double)j * ((double)m + 0.5) / (double)NMEL));
    }

    for (int idx = tid; idx < NMEL * MELW_STRIDE; idx += 256)
        ws[WS_MELW + idx] = 0.0f;

    // dense per-bin (ch, w), replicating TF MfccMelFilterbank
    const double mel_lo  = 1127.0 * log1p(20.0 / 700.0);
    const double mel_hi  = 1127.0 * log1p(7600.0 / 700.0);
    const double spacing = (mel_hi - mel_lo) / (NMEL + 1);
    for (int i = tid; i < NBINS; i += 256) {
        if (i < 2 || i > 486) {      // start_index=2, end_index=486
            chloc[i] = -100; wloc[i] = 0.0f;
        } else {
            double melf = 1127.0 * log1p((double)i * 15.625 / 700.0);
            int ch = 0;
            while (ch < NMEL && (mel_lo + spacing * (ch + 1)) < melf) ch++;
            ch -= 1;                 // may be -1
            chloc[i] = ch;
            wloc[i]  = (float)((mel_lo + spacing * (ch + 2) - melf) / spacing);
        }
    }
    __syncthreads();

    // per-channel lo via parallel atomicMin
    for (int i = 2 + tid; i <= 486; i += 256) {
        int ch = chloc[i];
        if (ch >= 0)       atomicMin(&lo_s[ch], i);
        if (ch + 1 < NMEL) atomicMin(&lo_s[ch + 1], i);
    }
    __syncthreads();
    if (tid < NMEL) {
        int lo  = lo_s[tid];
        int lo4 = (lo == 0x7fffffff) ? 0 : (lo & ~3);
        lo_s[tid] = lo4;
        ((int*)(ws + WS_MSTART))[tid] = lo4;
    }
    __syncthreads();

    // scatter weights (x0.5: kernel computes 2X in the rfft unpack)
    for (int i = 2 + tid; i <= 486; i += 256) {
        int ch = chloc[i]; float wgt = wloc[i];
        if (ch >= 0)
            ws[WS_MELW + ch * MELW_STRIDE + (i - lo_s[ch])] = 0.5f * wgt;
        if (ch + 1 < NMEL)
            ws[WS_MELW + (ch + 1) * MELW_STRIDE + (i - lo_s[ch + 1])] = 0.5f * (1.0f - wgt);
    }
}

// ---- packed-f32 (VOP3P) complex helpers ----
typedef float vf2 __attribute__((ext_vector_type(2)));
union f2u { float2 f; vf2 v; };
__device__ __forceinline__ vf2 V(float2 a){ f2u u; u.f = a; return u.v; }
__device__ __forceinline__ float2 F(vf2 a){ f2u u; u.v = a; return u.f; }

__device__ __forceinline__ float2 pkadd(float2 af, float2 bf){
    vf2 d, a = V(af), b = V(bf);
    asm("v_pk_add_f32 %0, %1, %2" : "=v"(d) : "v"(a), "v"(b));
    return F(d);
}
__device__ __forceinline__ float2 pksub(float2 af, float2 bf){
    vf2 d, a = V(af), b = V(bf);
    asm("v_pk_add_f32 %0, %1, %2 neg_lo:[0,1] neg_hi:[0,1]" : "=v"(d) : "v"(a), "v"(b));
    return F(d);
}
// d = a + (-i)*b
__device__ __forceinline__ float2 pkaddmi(float2 af, float2 bf){
    vf2 d, a = V(af), b = V(bf);
    asm("v_pk_add_f32 %0, %1, %2 op_sel:[0,1] op_sel_hi:[1,0] neg_hi:[0,1]" : "=v"(d) : "v"(a), "v"(b));
    return F(d);
}
// d = a - (-i)*b
__device__ __forceinline__ float2 pksubmi(float2 af, float2 bf){
    vf2 d, a = V(af), b = V(bf);
    asm("v_pk_add_f32 %0, %1, %2 op_sel:[0,1] op_sel_hi:[1,0] neg_lo:[0,1]" : "=v"(d) : "v"(a), "v"(b));
    return F(d);
}
// d = a * w (complex, 2 ops)
__device__ __forceinline__ float2 cmulpk(float2 af, float2 wf){
    vf2 d, a = V(af), w = V(wf);
    asm("v_pk_mul_f32 %0, %1, %2 op_sel:[0,0] op_sel_hi:[0,1]" : "=v"(d) : "v"(a), "v"(w));
    asm("v_pk_fma_f32 %0, %1, %2, %0 op_sel:[1,1,0] op_sel_hi:[1,0,1] neg_lo:[1,0,0] neg_hi:[0,0,0]"
        : "+v"(d) : "v"(a), "v"(w));
    return F(d);
}
// E = (zk.x + zm.x, zk.y - zm.y)
__device__ __forceinline__ float2 pkE(float2 zkf, float2 zmf){
    vf2 d, zk = V(zkf), zm = V(zmf);
    asm("v_pk_add_f32 %0, %1, %2 neg_hi:[0,1]" : "=v"(d) : "v"(zk), "v"(zm));
    return F(d);
}
// O = (zk.y + zm.y, zm.x - zk.x)
__device__ __forceinline__ float2 pkO(float2 zkf, float2 zmf){
    vf2 d, zk = V(zkf), zm = V(zmf);
    asm("v_pk_add_f32 %0, %1, %2 op_sel:[1,1] op_sel_hi:[0,0] neg_hi:[1,0]" : "=v"(d) : "v"(zk), "v"(zm));
    return F(d);
}

#define S8C 0.70710678118654752440f

__device__ __forceinline__ void dft8(float2 v[8]) {
    float2 b0=pkadd(v[0],v[4]), b4=pksub(v[0],v[4]);
    float2 b1=pkadd(v[1],v[5]), b5=pksub(v[1],v[5]);
    float2 b2=pkadd(v[2],v[6]), b6=pksub(v[2],v[6]);
    float2 b3=pkadd(v[3],v[7]), b7=pksub(v[3],v[7]);
    float2 c0=pkadd(b0,b2), c2=pksub(b0,b2);
    float2 c1=pkadd(b1,b3), c3=pksub(b1,b3);
    float2 c4=pkaddmi(b4,b6), c6=pksubmi(b4,b6);
    float2 c5=pkaddmi(b5,b7), c7=pksubmi(b5,b7);
    float2 w1c5 = cmulpk(c5, make_float2(S8C, -S8C));
    float2 w3c7 = cmulpk(c7, make_float2(-S8C, -S8C));
    v[0]=pkadd(c0,c1);   v[4]=pksub(c0,c1);
    v[2]=pkaddmi(c2,c3); v[6]=pksubmi(c2,c3);
    v[1]=pkadd(c4,w1c5); v[5]=pksub(c4,w1c5);
    v[3]=pkadd(c6,w3c7); v[7]=pksub(c6,w3c7);
}

// dft8 specialized for v[5]=v[6]=v[7]=0
__device__ __forceinline__ void dft8_first(float2 v[8]) {
    float2 b0=pkadd(v[0],v[4]), b4=pksub(v[0],v[4]);
    float2 c0=pkadd(b0,v[2]), c2=pksub(b0,v[2]);
    float2 c1=pkadd(v[1],v[3]), c3=pksub(v[1],v[3]);
    float2 c4=pkaddmi(b4,v[2]), c6=pksubmi(b4,v[2]);
    float2 c5=pkaddmi(v[1],v[3]), c7=pksubmi(v[1],v[3]);
    float2 w1c5 = cmulpk(c5, make_float2(S8C, -S8C));
    float2 w3c7 = cmulpk(c7, make_float2(-S8C, -S8C));
    v[0]=pkadd(c0,c1);   v[4]=pksub(c0,c1);
    v[2]=pkaddmi(c2,c3); v[6]=pksubmi(c2,c3);
    v[1]=pkadd(c4,w1c5); v[5]=pksub(c4,w1c5);
    v[3]=pkadd(c6,w3c7); v[7]=pksub(c6,w3c7);
}

__global__ __launch_bounds__(256, 8)
void mfcc_kernel(const float* __restrict__ wave, const float* __restrict__ ws,
                 float* __restrict__ out) {
    // pool: staging = 16 rows x 327 half2 (20928 B); FFT phase: wave w's region =
    // its OWN 4 rows [w*1308, w*1308+1308) — SA/SB (1152 half2) fit inside.
    __shared__ __align__(16) __half2 pool[CHPG * ROWH2];   // 20928 B
    __shared__ __align__(16) float   lmall[8 * NMEL];      // 1280 B

    const int tid = threadIdx.x;
    // bijective chunked XCD swizzle: nwg = 3996 = 8*499 + 4
    const int b    = blockIdx.x;
    const int xcd  = b & 7;
    const int wgid = (xcd < 4 ? xcd * 500 : 2000 + (xcd - 4) * 499) + (b >> 3);
    const int cg   = wgid / 999;         // channel group 0..3
    const int f    = wgid - cg * 999;    // frame
    const int c0   = cg * CHPG;
    const int w    = tid >> 6;           // wave id 0..3
    const int l    = tid & 63;           // lane

    // ---- coalesced stage: 640 rows x 64B, Hann applied, transposed [ch][t] half ----
    {
        const float4* wp4 = (const float4*)(wave + (size_t)f * STEP * C_CH) + cg * 4;
        const float*  hannf = ws + WS_HANN;
        #pragma unroll
        for (int m = 0; m < 5; ++m) {
            const int j = tid + 256 * m;     // 0..1279
            const int p = j >> 2, g = j & 3; // p = t-pair 0..319
            float4 x0 = wp4[(size_t)(2 * p)     * 16 + g];
            float4 x1 = wp4[(size_t)(2 * p + 1) * 16 + g];
            float  h0 = hannf[2 * p], h1 = hannf[2 * p + 1];
            pool[(4*g+0)*ROWH2 + p] = __floats2half2_rn(x0.x * h0, x1.x * h1);
            pool[(4*g+1)*ROWH2 + p] = __floats2half2_rn(x0.y * h0, x1.y * h1);
            pool[(4*g+2)*ROWH2 + p] = __floats2half2_rn(x0.z * h0, x1.z * h1);
            pool[(4*g+3)*ROWH2 + p] = __floats2half2_rn(x0.w * h0, x1.w * h1);
        }
    }
    __syncthreads();
    // ---- below: strictly wave-private LDS (own 4 rows only); no more barriers ----

    // pre-pull q=1 channels (rows 4w+2, 4w+3) — clobbered by own q=0 FFT writes
    __half2 sA1[5], sB1[5];
    {
        const int r2 = (4*w+2)*ROWH2, r3 = (4*w+3)*ROWH2;
        #pragma unroll
        for (int r = 0; r < 5; ++r) {
            sA1[r] = pool[r2 + l + 64*r];
            sB1[r] = pool[r3 + l + 64*r];
        }
    }

    __half2* SA   = pool + w * PITCH_H2;
    __half2* SB   = SA + SPAD;
    float*   magA = (float*)SA;          // overlays (576 floats each)
    float*   magB = (float*)SB;
    float*   lmA  = lmall + (2 * w) * NMEL;
    float*   lmB  = lmA + NMEL;

    // per-lane twiddle bases: W = e^{-i theta} = (cos, -sin)
    float s2a, c2a, s3a, c3a, sua, cua;
    __sincosf((float)(l & 7) * (TWO_PI_F / 64.0f),  &s2a, &c2a);
    __sincosf((float)l       * (TWO_PI_F / 512.0f), &s3a, &c3a);
    __sincosf((float)l       * (TWO_PI_F / 1024.0f),&sua, &cua);
    const float2 tb2 = make_float2(c2a, -s2a);
    const float2 tb3 = make_float2(c3a, -s3a);
    const float2 bu  = make_float2(cua, -sua);

    // W16^r = (cos(pi r/8), -sin(pi r/8))
    const float C16[8] = {1.0f, 0.923879533f, 0.707106781f, 0.382683432f,
                          0.0f, -0.382683432f, -0.707106781f, -0.923879533f};
    const float S16[8] = {0.0f, 0.382683432f, 0.707106781f, 0.923879533f,
                          1.0f, 0.923879533f, 0.707106781f, 0.382683432f};

    // hoisted q-invariant twiddle ladders (R17 regime; twh NOT hoisted)
    float2 t2p[7], t3p[7];
    t2p[0] = tb2; t3p[0] = tb3;
    #pragma unroll
    for (int r = 1; r < 7; ++r) {
        t2p[r] = cmulpk(t2p[r - 1], tb2);
        t3p[r] = cmulpk(t3p[r - 1], tb3);
    }

    const int src = (64 - l) & 63;

    #pragma unroll 1
    for (int q = 0; q < 2; ++q) {
        const int chA = 4 * w + 2 * q;   // local channels chA, chA+1

        float2 a[8], c[8];
        if (q == 0) {
            const __half2* rA = pool + (4*w)*ROWH2;
            const __half2* rB = pool + (4*w+1)*ROWH2;
            #pragma unroll
            for (int r = 0; r < 8; ++r) {
                if (r < 5) {
                    a[r] = __half22float2(rA[l + 64*r]);
                    c[r] = __half22float2(rB[l + 64*r]);
                } else { a[r] = make_float2(0.f, 0.f); c[r] = make_float2(0.f, 0.f); }
            }
        } else {
            #pragma unroll
            for (int r = 0; r < 8; ++r) {
                if (r < 5) {
                    a[r] = __half22float2(sA1[r]);
                    c[r] = __half22float2(sB1[r]);
                } else { a[r] = make_float2(0.f, 0.f); c[r] = make_float2(0.f, 0.f); }
            }
        }

        // ---- stage 1 ----
        dft8_first(a); dft8_first(c);
        #pragma unroll
        for (int k = 0; k < 8; ++k) {
            const int i = 8 * l + k;
            SA[i + (i >> 3)] = __floats2half2_rn(a[k].x, a[k].y);
            SB[i + (i >> 3)] = __floats2half2_rn(c[k].x, c[k].y);
        }

        // ---- stage 2: twiddle W64^{(l&7) r} ----
        #pragma unroll
        for (int r = 0; r < 8; ++r) {
            const int i = l + 64 * r;
            a[r] = __half22float2(SA[i + (i >> 3)]);
            c[r] = __half22float2(SB[i + (i >> 3)]);
        }
        #pragma unroll
        for (int r = 1; r < 8; ++r) { a[r] = cmulpk(a[r], t2p[r-1]); c[r] = cmulpk(c[r], t2p[r-1]); }
        dft8(a); dft8(c);
        {
            const int idxD = ((l >> 3) << 6) + (l & 7);
            #pragma unroll
            for (int k = 0; k < 8; ++k) {
                const int i = idxD + 8 * k;
                SA[i + (i >> 3)] = __floats2half2_rn(a[k].x, a[k].y);
                SB[i + (i >> 3)] = __floats2half2_rn(c[k].x, c[k].y);
            }
        }

        // ---- stage 3: twiddle W512^{l r}; result in registers ----
        #pragma unroll
        for (int r = 0; r < 8; ++r) {
            const int i = l + 64 * r;
            a[r] = __half22float2(SA[i + (i >> 3)]);
            c[r] = __half22float2(SB[i + (i >> 3)]);
        }
        #pragma unroll
        for (int r = 1; r < 8; ++r) { a[r] = cmulpk(a[r], t3p[r-1]); c[r] = cmulpk(c[r], t3p[r-1]); }
        dft8(a); dft8(c);
        // lane l holds Z[l + 64k] in a[k]/c[k]

        // ---- per-r conjugate-partner shuffle + rfft unpack + magnitude ----
        #pragma unroll
        for (int r = 0; r < 8; ++r) {
            float2 ta, tc;
            ta.x = __shfl(a[7 - r].x, src); ta.y = __shfl(a[7 - r].y, src);
            tc.x = __shfl(c[7 - r].x, src); tc.y = __shfl(c[7 - r].y, src);
            if (l == 0) { ta = a[(8 - r) & 7]; tc = c[(8 - r) & 7]; }
            float2 twr = cmulpk(bu, make_float2(C16[r], -S16[r]));   // W1024^{l+64r}
            float2 Ea = pkE(a[r], ta), Oa = pkO(a[r], ta);
            float2 Xa = pkadd(Ea, cmulpk(Oa, twr));
            float2 Ec = pkE(c[r], tc), Oc = pkO(c[r], tc);
            float2 Xc = pkadd(Ec, cmulpk(Oc, twr));
            magA[l + 64 * r] = __builtin_amdgcn_sqrtf(Xa.x * Xa.x + Xa.y * Xa.y);
            magB[l + 64 * r] = __builtin_amdgcn_sqrtf(Xc.x * Xc.x + Xc.y * Xc.y);
        }
        magA[512 + l] = (l == 0) ? 2.0f * fabsf(a[0].x - a[0].y) : 0.0f;
        magB[512 + l] = (l == 0) ? 2.0f * fabsf(c[0].x - c[0].y) : 0.0f;

        // ---- mel: lanes<40, shared weight row, both channels; lm holds log2 ----
        if (l < NMEL) {
            const int lo4 = ((const int*)(ws + WS_MSTART))[l];
            const float4* wrow = (const float4*)(ws + WS_MELW + l * MELW_STRIDE);
            const float4* mrA  = (const float4*)(magA + lo4);
            const float4* mrB  = (const float4*)(magB + lo4);
            float accA = 0.0f, accB = 0.0f;
            #pragma unroll
            for (int j = 0; j < MELW_STRIDE / 4; ++j) {
                float4 wv = wrow[j];
                float4 va = mrA[j], vb = mrB[j];
                accA += wv.x * va.x + wv.y * va.y + wv.z * va.z + wv.w * va.w;
                accB += wv.x * vb.x + wv.y * vb.y + wv.z * vb.z + wv.w * vb.w;
            }
            lmA[l] = __builtin_amdgcn_logf(accA + 1e-12f);   // log2; ln2 folded into DCT
            lmB[l] = __builtin_amdgcn_logf(accB + 1e-12f);
        }

        // ---- DCT + clip + store (lanes 0..12), both channels ----
        if (l < NMFCC) {
            const float4* drow = (const float4*)(ws + WS_DCT + l * NMEL);
            const float4* lrA  = (const float4*)lmA;
            const float4* lrB  = (const float4*)lmB;
            float accA = 0.0f, accB = 0.0f;
            #pragma unroll
            for (int j = 0; j < NMEL / 4; ++j) {
                float4 dv = drow[j];
                float4 va = lrA[j], vb = lrB[j];
                accA += dv.x * va.x + dv.y * va.y + dv.z * va.z + dv.w * va.w;
                accB += dv.x * vb.x + dv.y * vb.y + dv.z * vb.z + dv.w * vb.w;
            }
            accA = fminf(10.0f, fmaxf(-10.0f, accA));
            accB = fminf(10.0f, fmaxf(-10.0f, accB));
            out[((size_t)(c0 + chA)     * F_FRAMES + f) * NMFCC + l] = accA;
            out[((size_t)(c0 + chA + 1) * F_FRAMES + f) * NMFCC + l] = accB;
        }
    }
}

extern "C" void kernel_launch(void* const* d_in, const int* in_sizes, int n_in,
                              void* d_out, int out_size, void* d_ws, size_t ws_size,
                              hipStream_t stream) {
    const float* wave = (const float*)d_in[0];
    float* out = (float*)d_out;
    float* ws  = (float*)d_ws;
    hipLaunchKernelGGL(setup_tables, dim3(1), dim3(256), 0, stream, ws);
    hipLaunchKernelGGL(mfcc_kernel, dim3(NBLK), dim3(256), 0, stream, wave, ws, out);
}

// Round 20
// 78.312 us; speedup vs baseline: 1.1821x; 1.0115x over previous
//
#include <hip/hip_runtime.h>
#include <hip/hip_fp16.h>
#include <math.h>

#define C_CH       64
#define F_FRAMES   999
#define TOTAL_SAMP 320000
#define FRAME_LEN  640
#define STEP       320
#define N2         512      // complex FFT size (real FFT 1024)
#define NBINS      513
#define NMEL       40
#define NMFCC      13
#define CHPG       16       // channels per block (one 64B line)
#define NCHG       4        // channel groups
#define NBLK       (F_FRAMES * NCHG)   // 3996 blocks
#define MELW_STRIDE 72      // multiple of 4
#define ROWH2      324      // half2 per staging row (>=320; 324%8==4 -> staging writes 2-way)
#define PITCH_H2   (4 * ROWH2)         // 1296 half2 = 5184 B: wave's 4 rows = its FFT region

#define TWO_PI_F 6.28318530717958647692f
#define LN2_F    0.69314718055994530942f

// d_ws float layout (all offsets multiples of 4 -> float4-aligned)
#define WS_HANN   0        // 640
#define WS_DCT    640      // 520  (pre-scaled by ln2; lm holds log2)
#define WS_MSTART 1160     // 40 ints (lo4, 4-aligned bin start)
#define WS_MELW   1200     // 40*72 = 2880, zero-padded rows, PRE-SCALED by 0.5
#define WS_TOTAL  4080

__global__ __launch_bounds__(256)
void setup_tables(float* __restrict__ ws) {
    __shared__ float wloc[NBINS];
    __shared__ int   chloc[NBINS];
    __shared__ int   lo_s[NMEL];
    const int tid = threadIdx.x;

    if (tid < NMEL) lo_s[tid] = 0x7fffffff;

    for (int n = tid; n < FRAME_LEN; n += 256)
        ws[WS_HANN + n] = 0.5f - 0.5f * cosf((float)n * (TWO_PI_F / 640.0f));

    // DCT pre-scaled by ln2 (kernel's lm holds log2(mel))
    for (int idx = tid; idx < NMFCC * NMEL; idx += 256) {
        int j = idx / NMEL, m = idx - j * NMEL;
        ws[WS_DCT + idx] = LN2_F * 0.223606797749978969f *
            cosf((float)(M_PI * (double)j * ((double)m + 0.5) / (double)NMEL));
    }

    for (int idx = tid; idx < NMEL * MELW_STRIDE; idx += 256)
        ws[WS_MELW + idx] = 0.0f;

    // dense per-bin (ch, w), replicating TF MfccMelFilterbank
    const double mel_lo  = 1127.0 * log1p(20.0 / 700.0);
    const double mel_hi  = 1127.0 * log1p(7600.0 / 700.0);
    const double spacing = (mel_hi - mel_lo) / (NMEL + 1);
    for (int i = tid; i < NBINS; i += 256) {
        if (i < 2 || i > 486) {      // start_index=2, end_index=486
            chloc[i] = -100; wloc[i] = 0.0f;
        } else {
            double melf = 1127.0 * log1p((double)i * 15.625 / 700.0);
            int ch = 0;
            while (ch < NMEL && (mel_lo + spacing * (ch + 1)) < melf) ch++;
            ch -= 1;                 // may be -1
            chloc[i] = ch;
            wloc[i]  = (float)((mel_lo + spacing * (ch + 2) - melf) / spacing);
        }
    }
    __syncthreads();

    // per-channel lo via parallel atomicMin
    for (int i = 2 + tid; i <= 486; i += 256) {
        int ch = chloc[i];
        if (ch >= 0)       atomicMin(&lo_s[ch], i);
        if (ch + 1 < NMEL) atomicMin(&lo_s[ch + 1], i);
    }
    __syncthreads();
    if (tid < NMEL) {
        int lo  = lo_s[tid];
        int lo4 = (lo == 0x7fffffff) ? 0 : (lo & ~3);
        lo_s[tid] = lo4;
        ((int*)(ws + WS_MSTART))[tid] = lo4;
    }
    __syncthreads();

    // scatter weights (x0.5: kernel computes 2X in the rfft unpack)
    for (int i = 2 + tid; i <= 486; i += 256) {
        int ch = chloc[i]; float wgt = wloc[i];
        if (ch >= 0)
            ws[WS_MELW + ch * MELW_STRIDE + (i - lo_s[ch])] = 0.5f * wgt;
        if (ch + 1 < NMEL)
            ws[WS_MELW + (ch + 1) * MELW_STRIDE + (i - lo_s[ch + 1])] = 0.5f * (1.0f - wgt);
    }
}

// ---- packed-f32 (VOP3P) complex helpers ----
typedef float vf2 __attribute__((ext_vector_type(2)));
union f2u { float2 f; vf2 v; };
__device__ __forceinline__ vf2 V(float2 a){ f2u u; u.f = a; return u.v; }
__device__ __forceinline__ float2 F(vf2 a){ f2u u; u.v = a; return u.f; }

__device__ __forceinline__ float2 pkadd(float2 af, float2 bf){
    vf2 d, a = V(af), b = V(bf);
    asm("v_pk_add_f32 %0, %1, %2" : "=v"(d) : "v"(a), "v"(b));
    return F(d);
}
__device__ __forceinline__ float2 pksub(float2 af, float2 bf){
    vf2 d, a = V(af), b = V(bf);
    asm("v_pk_add_f32 %0, %1, %2 neg_lo:[0,1] neg_hi:[0,1]" : "=v"(d) : "v"(a), "v"(b));
    return F(d);
}
// d = a + (-i)*b
__device__ __forceinline__ float2 pkaddmi(float2 af, float2 bf){
    vf2 d, a = V(af), b = V(bf);
    asm("v_pk_add_f32 %0, %1, %2 op_sel:[0,1] op_sel_hi:[1,0] neg_hi:[0,1]" : "=v"(d) : "v"(a), "v"(b));
    return F(d);
}
// d = a - (-i)*b
__device__ __forceinline__ float2 pksubmi(float2 af, float2 bf){
    vf2 d, a = V(af), b = V(bf);
    asm("v_pk_add_f32 %0, %1, %2 op_sel:[0,1] op_sel_hi:[1,0] neg_lo:[0,1]" : "=v"(d) : "v"(a), "v"(b));
    return F(d);
}
// d = a * w (complex, 2 ops)
__device__ __forceinline__ float2 cmulpk(float2 af, float2 wf){
    vf2 d, a = V(af), w = V(wf);
    asm("v_pk_mul_f32 %0, %1, %2 op_sel:[0,0] op_sel_hi:[0,1]" : "=v"(d) : "v"(a), "v"(w));
    asm("v_pk_fma_f32 %0, %1, %2, %0 op_sel:[1,1,0] op_sel_hi:[1,0,1] neg_lo:[1,0,0] neg_hi:[0,0,0]"
        : "+v"(d) : "v"(a), "v"(w));
    return F(d);
}
// E = (zk.x + zm.x, zk.y - zm.y)
__device__ __forceinline__ float2 pkE(float2 zkf, float2 zmf){
    vf2 d, zk = V(zkf), zm = V(zmf);
    asm("v_pk_add_f32 %0, %1, %2 neg_hi:[0,1]" : "=v"(d) : "v"(zk), "v"(zm));
    return F(d);
}
// O = (zk.y + zm.y, zm.x - zk.x)
__device__ __forceinline__ float2 pkO(float2 zkf, float2 zmf){
    vf2 d, zk = V(zkf), zm = V(zmf);
    asm("v_pk_add_f32 %0, %1, %2 op_sel:[1,1] op_sel_hi:[0,0] neg_hi:[1,0]" : "=v"(d) : "v"(zk), "v"(zm));
    return F(d);
}

#define S8C 0.70710678118654752440f

__device__ __forceinline__ void dft8(float2 v[8]) {
    float2 b0=pkadd(v[0],v[4]), b4=pksub(v[0],v[4]);
    float2 b1=pkadd(v[1],v[5]), b5=pksub(v[1],v[5]);
    float2 b2=pkadd(v[2],v[6]), b6=pksub(v[2],v[6]);
    float2 b3=pkadd(v[3],v[7]), b7=pksub(v[3],v[7]);
    float2 c0=pkadd(b0,b2), c2=pksub(b0,b2);
    float2 c1=pkadd(b1,b3), c3=pksub(b1,b3);
    float2 c4=pkaddmi(b4,b6), c6=pksubmi(b4,b6);
    float2 c5=pkaddmi(b5,b7), c7=pksubmi(b5,b7);
    float2 w1c5 = cmulpk(c5, make_float2(S8C, -S8C));
    float2 w3c7 = cmulpk(c7, make_float2(-S8C, -S8C));
    v[0]=pkadd(c0,c1);   v[4]=pksub(c0,c1);
    v[2]=pkaddmi(c2,c3); v[6]=pksubmi(c2,c3);
    v[1]=pkadd(c4,w1c5); v[5]=pksub(c4,w1c5);
    v[3]=pkadd(c6,w3c7); v[7]=pksub(c6,w3c7);
}

// dft8 specialized for v[5]=v[6]=v[7]=0
__device__ __forceinline__ void dft8_first(float2 v[8]) {
    float2 b0=pkadd(v[0],v[4]), b4=pksub(v[0],v[4]);
    float2 c0=pkadd(b0,v[2]), c2=pksub(b0,v[2]);
    float2 c1=pkadd(v[1],v[3]), c3=pksub(v[1],v[3]);
    float2 c4=pkaddmi(b4,v[2]), c6=pksubmi(b4,v[2]);
    float2 c5=pkaddmi(v[1],v[3]), c7=pksubmi(v[1],v[3]);
    float2 w1c5 = cmulpk(c5, make_float2(S8C, -S8C));
    float2 w3c7 = cmulpk(c7, make_float2(-S8C, -S8C));
    v[0]=pkadd(c0,c1);   v[4]=pksub(c0,c1);
    v[2]=pkaddmi(c2,c3); v[6]=pksubmi(c2,c3);
    v[1]=pkadd(c4,w1c5); v[5]=pksub(c4,w1c5);
    v[3]=pkadd(c6,w3c7); v[7]=pksub(c6,w3c7);
}

// 8-byte interleaved channel pair for b64 LDS ops
struct __align__(8) h2pair { __half2 a, b; };

__global__ __launch_bounds__(256, 8)
void mfcc_kernel(const float* __restrict__ wave, const float* __restrict__ ws,
                 float* __restrict__ out) {
    // pool: staging = 16 rows x 324 half2 (20736 B); FFT phase: wave w's region =
    // its OWN 4 rows [w*1296, (w+1)*1296) — interleaved SAB (1150 half2) fits inside.
    __shared__ __align__(16) __half2 pool[CHPG * ROWH2];   // 20736 B
    __shared__ __align__(16) float   lmall[8 * NMEL];      // 1280 B

    const int tid = threadIdx.x;
    // bijective chunked XCD swizzle: nwg = 3996 = 8*499 + 4
    const int b    = blockIdx.x;
    const int xcd  = b & 7;
    const int wgid = (xcd < 4 ? xcd * 500 : 2000 + (xcd - 4) * 499) + (b >> 3);
    const int cg   = wgid / 999;         // channel group 0..3
    const int f    = wgid - cg * 999;    // frame
    const int c0   = cg * CHPG;
    const int w    = tid >> 6;           // wave id 0..3
    const int l    = tid & 63;           // lane

    // ---- coalesced stage: 640 rows x 64B, Hann applied, transposed [ch][t] half ----
    // ROWH2 = 324 -> 4*ROWH2 ≡ 16 (mod 32): the four (l&3) groups split banks 0-15 /
    // 16-31 evenly -> 2 lanes/bank (free floor), vs 4-way at 327.
    {
        const float4* wp4 = (const float4*)(wave + (size_t)f * STEP * C_CH) + cg * 4;
        const float*  hannf = ws + WS_HANN;
        #pragma unroll
        for (int m = 0; m < 5; ++m) {
            const int j = tid + 256 * m;     // 0..1279
            const int p = j >> 2, g = j & 3; // p = t-pair 0..319
            float4 x0 = wp4[(size_t)(2 * p)     * 16 + g];
            float4 x1 = wp4[(size_t)(2 * p + 1) * 16 + g];
            float  h0 = hannf[2 * p], h1 = hannf[2 * p + 1];
            pool[(4*g+0)*ROWH2 + p] = __floats2half2_rn(x0.x * h0, x1.x * h1);
            pool[(4*g+1)*ROWH2 + p] = __floats2half2_rn(x0.y * h0, x1.y * h1);
            pool[(4*g+2)*ROWH2 + p] = __floats2half2_rn(x0.z * h0, x1.z * h1);
            pool[(4*g+3)*ROWH2 + p] = __floats2half2_rn(x0.w * h0, x1.w * h1);
        }
    }
    __syncthreads();
    // ---- below: strictly wave-private LDS (own 4 rows only); no more barriers ----

    // pre-pull q=1 channels (rows 4w+2, 4w+3) — clobbered by own q=0 FFT writes
    __half2 sA1[5], sB1[5];
    {
        const int r2 = (4*w+2)*ROWH2, r3 = (4*w+3)*ROWH2;
        #pragma unroll
        for (int r = 0; r < 5; ++r) {
            sA1[r] = pool[r2 + l + 64*r];
            sB1[r] = pool[r3 + l + 64*r];
        }
    }

    // interleaved FFT buffer: SAB[ip] = {chanA[ip], chanB[ip]} -> one b64 per pair
    h2pair* SAB  = (h2pair*)(pool + w * PITCH_H2);
    float*  magA = (float*)(pool + w * PITCH_H2);   // overlay after FFT consumed
    float*  magB = magA + 576;                      // 1152 floats <= 1296 region
    float*  lmA  = lmall + (2 * w) * NMEL;
    float*  lmB  = lmA + NMEL;

    // per-lane twiddle bases: W = e^{-i theta} = (cos, -sin)
    float s2a, c2a, s3a, c3a, sua, cua;
    __sincosf((float)(l & 7) * (TWO_PI_F / 64.0f),  &s2a, &c2a);
    __sincosf((float)l       * (TWO_PI_F / 512.0f), &s3a, &c3a);
    __sincosf((float)l       * (TWO_PI_F / 1024.0f),&sua, &cua);
    const float2 tb2 = make_float2(c2a, -s2a);
    const float2 tb3 = make_float2(c3a, -s3a);
    const float2 bu  = make_float2(cua, -sua);

    // W16^r = (cos(pi r/8), -sin(pi r/8))
    const float C16[8] = {1.0f, 0.923879533f, 0.707106781f, 0.382683432f,
                          0.0f, -0.382683432f, -0.707106781f, -0.923879533f};
    const float S16[8] = {0.0f, 0.382683432f, 0.707106781f, 0.923879533f,
                          1.0f, 0.923879533f, 0.707106781f, 0.382683432f};

    // hoisted q-invariant twiddle ladders (twh NOT hoisted — R18 spill lesson)
    float2 t2p[7], t3p[7];
    t2p[0] = tb2; t3p[0] = tb3;
    #pragma unroll
    for (int r = 1; r < 7; ++r) {
        t2p[r] = cmulpk(t2p[r - 1], tb2);
        t3p[r] = cmulpk(t3p[r - 1], tb3);
    }

    const int src = (64 - l) & 63;

    #pragma unroll 1
    for (int q = 0; q < 2; ++q) {
        const int chA = 4 * w + 2 * q;   // local channels chA, chA+1

        float2 a[8], c[8];
        if (q == 0) {
            const __half2* rA = pool + (4*w)*ROWH2;
            const __half2* rB = pool + (4*w+1)*ROWH2;
            #pragma unroll
            for (int r = 0; r < 8; ++r) {
                if (r < 5) {
                    a[r] = __half22float2(rA[l + 64*r]);
                    c[r] = __half22float2(rB[l + 64*r]);
                } else { a[r] = make_float2(0.f, 0.f); c[r] = make_float2(0.f, 0.f); }
            }
        } else {
            #pragma unroll
            for (int r = 0; r < 8; ++r) {
                if (r < 5) {
                    a[r] = __half22float2(sA1[r]);
                    c[r] = __half22float2(sB1[r]);
                } else { a[r] = make_float2(0.f, 0.f); c[r] = make_float2(0.f, 0.f); }
            }
        }

        // ---- stage 1: one b64 store per k (A,B pair) ----
        dft8_first(a); dft8_first(c);
        #pragma unroll
        for (int k = 0; k < 8; ++k) {
            const int i = 8 * l + k;
            h2pair pr; pr.a = __floats2half2_rn(a[k].x, a[k].y);
                       pr.b = __floats2half2_rn(c[k].x, c[k].y);
            SAB[i + (i >> 3)] = pr;
        }

        // ---- stage 2: one b64 load per r; twiddle W64^{(l&7) r} ----
        #pragma unroll
        for (int r = 0; r < 8; ++r) {
            const int i = l + 64 * r;
            h2pair pr = SAB[i + (i >> 3)];
            a[r] = __half22float2(pr.a);
            c[r] = __half22float2(pr.b);
        }
        #pragma unroll
        for (int r = 1; r < 8; ++r) { a[r] = cmulpk(a[r], t2p[r-1]); c[r] = cmulpk(c[r], t2p[r-1]); }
        dft8(a); dft8(c);
        {
            const int idxD = ((l >> 3) << 6) + (l & 7);
            #pragma unroll
            for (int k = 0; k < 8; ++k) {
                const int i = idxD + 8 * k;
                h2pair pr; pr.a = __floats2half2_rn(a[k].x, a[k].y);
                           pr.b = __floats2half2_rn(c[k].x, c[k].y);
                SAB[i + (i >> 3)] = pr;
            }
        }

        // ---- stage 3: one b64 load per r; twiddle W512^{l r}; result in registers ----
        #pragma unroll
        for (int r = 0; r < 8; ++r) {
            const int i = l + 64 * r;
            h2pair pr = SAB[i + (i >> 3)];
            a[r] = __half22float2(pr.a);
            c[r] = __half22float2(pr.b);
        }
        #pragma unroll
        for (int r = 1; r < 8; ++r) { a[r] = cmulpk(a[r], t3p[r-1]); c[r] = cmulpk(c[r], t3p[r-1]); }
        dft8(a); dft8(c);
        // lane l holds Z[l + 64k] in a[k]/c[k]

        // ---- per-r conjugate-partner shuffle + rfft unpack + magnitude ----
        #pragma unroll
        for (int r = 0; r < 8; ++r) {
            float2 ta, tc;
            ta.x = __shfl(a[7 - r].x, src); ta.y = __shfl(a[7 - r].y, src);
            tc.x = __shfl(c[7 - r].x, src); tc.y = __shfl(c[7 - r].y, src);
            if (l == 0) { ta = a[(8 - r) & 7]; tc = c[(8 - r) & 7]; }
            float2 twr = cmulpk(bu, make_float2(C16[r], -S16[r]));   // W1024^{l+64r}
            float2 Ea = pkE(a[r], ta), Oa = pkO(a[r], ta);
            float2 Xa = pkadd(Ea, cmulpk(Oa, twr));
            float2 Ec = pkE(c[r], tc), Oc = pkO(c[r], tc);
            float2 Xc = pkadd(Ec, cmulpk(Oc, twr));
            magA[l + 64 * r] = __builtin_amdgcn_sqrtf(Xa.x * Xa.x + Xa.y * Xa.y);
            magB[l + 64 * r] = __builtin_amdgcn_sqrtf(Xc.x * Xc.x + Xc.y * Xc.y);
        }
        magA[512 + l] = (l == 0) ? 2.0f * fabsf(a[0].x - a[0].y) : 0.0f;
        magB[512 + l] = (l == 0) ? 2.0f * fabsf(c[0].x - c[0].y) : 0.0f;

        // ---- mel: lanes<40, shared weight row, both channels; lm holds log2 ----
        if (l < NMEL) {
            const int lo4 = ((const int*)(ws + WS_MSTART))[l];
            const float4* wrow = (const float4*)(ws + WS_MELW + l * MELW_STRIDE);
            const float4* mrA  = (const float4*)(magA + lo4);
            const float4* mrB  = (const float4*)(magB + lo4);
            float accA = 0.0f, accB = 0.0f;
            #pragma unroll
            for (int j = 0; j < MELW_STRIDE / 4; ++j) {
                float4 wv = wrow[j];
                float4 va = mrA[j], vb = mrB[j];
                accA += wv.x * va.x + wv.y * va.y + wv.z * va.z + wv.w * va.w;
                accB += wv.x * vb.x + wv.y * vb.y + wv.z * vb.z + wv.w * vb.w;
            }
            lmA[l] = __builtin_amdgcn_logf(accA + 1e-12f);   // log2; ln2 folded into DCT
            lmB[l] = __builtin_amdgcn_logf(accB + 1e-12f);
        }

        // ---- DCT + clip + store (lanes 0..12), both channels ----
        if (l < NMFCC) {
            const float4* drow = (const float4*)(ws + WS_DCT + l * NMEL);
            const float4* lrA  = (const float4*)lmA;
            const float4* lrB  = (const float4*)lmB;
            float accA = 0.0f, accB = 0.0f;
            #pragma unroll
            for (int j = 0; j < NMEL / 4; ++j) {
                float4 dv = drow[j];
                float4 va = lrA[j], vb = lrB[j];
                accA += dv.x * va.x + dv.y * va.y + dv.z * va.z + dv.w * va.w;
                accB += dv.x * vb.x + dv.y * vb.y + dv.z * vb.z + dv.w * vb.w;
            }
            accA = fminf(10.0f, fmaxf(-10.0f, accA));
            accB = fminf(10.0f, fmaxf(-10.0f, accB));
            out[((size_t)(c0 + chA)     * F_FRAMES + f) * NMFCC + l] = accA;
            out[((size_t)(c0 + chA + 1) * F_FRAMES + f) * NMFCC + l] = accB;
        }
    }
}

extern "C" void kernel_launch(void* const* d_in, const int* in_sizes, int n_in,
                              void* d_out, int out_size, void* d_ws, size_t ws_size,
                              hipStream_t stream) {
    const float* wave = (const float*)d_in[0];
    float* out = (float*)d_out;
    float* ws  = (float*)d_ws;
    hipLaunchKernelGGL(setup_tables, dim3(1), dim3(256), 0, stream, ws);
    hipLaunchKernelGGL(mfcc_kernel, dim3(NBLK), dim3(256), 0, stream, wave, ws, out);
}